// Round 16
// baseline (1657.253 us; speedup 1.0000x reference)
//
#include <hip/hip_runtime.h>

#define FN   128    // nodes per graph
#define HDIM 128    // hidden dim
#define NH   4      // heads, layer 0
#define HSZ  32     // head dim, layer 0
#define EB   1024   // base edges per graph
#define ET   1152   // edges incl. self loops
#define RSW  132    // padded LDS row stride (words)

typedef __attribute__((ext_vector_type(8))) short bf16x8;
typedef __attribute__((ext_vector_type(4))) float f32x4;
typedef unsigned int u32;
typedef unsigned short u16;

union U8 { bf16x8 v; u32 u[4]; };

__device__ __forceinline__ u32 pack_hl(float v) {
  const u32 u = __float_as_uint(v);
  const u32 hib = u & 0xFFFF0000u;
  const float lo = v - __uint_as_float(hib);
  return hib | (__float_as_uint(lo) >> 16);
}
__device__ __forceinline__ float unpack_val(u32 p) {
  return __uint_as_float(p & 0xFFFF0000u) + __uint_as_float(p << 16);
}
__device__ __forceinline__ float lrelu(float v) {
  return (v > 0.f) ? v : 0.2f * v;
}

__device__ __forceinline__ void unpack_frag(const u32* __restrict__ q,
                                            bf16x8& hi, bf16x8& lo)
{
  const uint4 p0 = *(const uint4*)(q);
  const uint4 p1 = *(const uint4*)(q + 4);
  U8 H, L;
  H.u[0] = (p0.x >> 16) | (p0.y & 0xFFFF0000u);
  L.u[0] = (p0.x & 0xFFFFu) | (p0.y << 16);
  H.u[1] = (p0.z >> 16) | (p0.w & 0xFFFF0000u);
  L.u[1] = (p0.z & 0xFFFFu) | (p0.w << 16);
  H.u[2] = (p1.x >> 16) | (p1.y & 0xFFFF0000u);
  L.u[2] = (p1.x & 0xFFFFu) | (p1.y << 16);
  H.u[3] = (p1.z >> 16) | (p1.w & 0xFFFF0000u);
  L.u[3] = (p1.z & 0xFFFFu) | (p1.w << 16);
  hi = H.v; lo = L.v;
}

// ---------------- W -> split bf16 hi/lo, B-fragment layout (r3-verified) ----
__global__ __launch_bounds__(256) void prep_w_kernel(
    const float* __restrict__ g0w, const float* __restrict__ g1w,
    u16* __restrict__ wf)
{
  const int idx = blockIdx.x * 256 + threadIdx.x;   // 32768 total
  const int layer = idx >> 14;
  const int r = idx & 16383;
  const int c  = r >> 11;
  const int kc = (r >> 9) & 3;
  const int l  = (r >> 3) & 63;
  const int j  = r & 7;
  const int k = kc * 32 + (l >> 4) * 8 + j;
  const int n = c * 16 + (l & 15);
  const float* W = layer ? g1w : g0w;
  const float v = W[k * HDIM + n];
  const u32 u = __float_as_uint(v);
  const u32 hib = u & 0xFFFF0000u;
  const float lo = v - __uint_as_float(hib);
  wf[layer * 32768 + r]         = (u16)(u >> 16);
  wf[layer * 32768 + 16384 + r] = (u16)(__float_as_uint(lo) >> 16);
}

// MFMA GEMM, 8 waves/graph (r12/r14-verified): wave tile 32 cols x 64 rows.
__device__ __forceinline__ void mfma_gemm_acc(const u32* __restrict__ F,
                                              const u16* __restrict__ wf,
                                              int lw, int lane, f32x4 acc[4][2])
{
  const int cg = lw & 3, rh = lw >> 2;
  const int m = lane & 15, quad = lane >> 4;

  #pragma unroll
  for (int s = 0; s < 4; ++s)
    #pragma unroll
    for (int ct = 0; ct < 2; ++ct) acc[s][ct] = (f32x4){0.f, 0.f, 0.f, 0.f};

  const u16* bbase = wf + (cg * 8) * 512 + lane * 8;   // ct +2048, kc +512

  #pragma unroll
  for (int kc = 0; kc < 4; ++kc) {
    bf16x8 bhi[2], blo[2];
    #pragma unroll
    for (int ct = 0; ct < 2; ++ct) {
      const u16* bp = bbase + ct * 2048 + kc * 512;
      bhi[ct] = *(const bf16x8*)bp;
      blo[ct] = *(const bf16x8*)(bp + 16384);
    }
    #pragma unroll
    for (int s = 0; s < 4; ++s) {
      const u32* ap = F + (rh * 64 + s * 16 + m) * RSW + quad * 8 + kc * 32;
      bf16x8 ahi, alo;
      unpack_frag(ap, ahi, alo);
      #pragma unroll
      for (int ct = 0; ct < 2; ++ct) {
        acc[s][ct] = __builtin_amdgcn_mfma_f32_16x16x32_bf16(ahi, bhi[ct], acc[s][ct], 0, 0, 0);
        acc[s][ct] = __builtin_amdgcn_mfma_f32_16x16x32_bf16(alo, bhi[ct], acc[s][ct], 0, 0, 0);
        acc[s][ct] = __builtin_amdgcn_mfma_f32_16x16x32_bf16(ahi, blo[ct], acc[s][ct], 0, 0, 0);
      }
    }
  }
}

// store acc -> plain f32 (in-place into F); C/D: col = lane&15, row = quad*4+r
__device__ __forceinline__ void store_acc(float* __restrict__ sg, int lw,
                                          int lane, const f32x4 acc[4][2])
{
  const int cg = lw & 3, rh = lw >> 2;
  const int m = lane & 15, quad = lane >> 4;
  #pragma unroll
  for (int s = 0; s < 4; ++s) {
    const int row0 = rh * 64 + s * 16 + quad * 4;
    #pragma unroll
    for (int ct = 0; ct < 2; ++ct)
      #pragma unroll
      for (int r = 0; r < 4; ++r)
        sg[(row0 + r) * RSW + cg * 32 + ct * 16 + m] = acc[s][ct][r];
  }
}

// ---------------- fused GNN: 1024 threads, TWO graphs per block ------------
__global__ __launch_bounds__(1024) void gnn_fused_kernel(
    const float* __restrict__ x, const int* __restrict__ ei,
    const float* __restrict__ w_in, const float* __restrict__ b_in,
    const float* __restrict__ g0as, const float* __restrict__ g0ad,
    const float* __restrict__ g0b,
    const float* __restrict__ bn0g, const float* __restrict__ bn0b,
    const float* __restrict__ bn0m, const float* __restrict__ bn0v,
    const float* __restrict__ g1as, const float* __restrict__ g1ad,
    const float* __restrict__ g1b,
    const float* __restrict__ bn1g, const float* __restrict__ bn1b,
    const float* __restrict__ bn1m, const float* __restrict__ bn1v,
    const float* __restrict__ w1, const float* __restrict__ b1,
    const float* __restrict__ w2, const float* __restrict__ b2,
    const u16* __restrict__ wf,
    float* __restrict__ out)
{
  __shared__ u32   Fb[2 * FN * RSW];   // 135168 B: per-graph packed feat <-> f32 sg
  __shared__ int   s_src[ET];          // src | dst<<8 (SHARED topology)
  __shared__ int   s_rp[FN + 1];
  __shared__ float s_scr[3072];        // per graph: es 512 | ed 512 | rs 512
  __shared__ float s_bn[512];          // folded BN consts: [l*256 + {q:0,r:128} + col]

  const int t = threadIdx.x;
  const int b = blockIdx.x;
  const int g = t >> 9;                // graph within block
  const int u = t & 511;               // per-graph thread
  const int lane = t & 63;
  const int lw = (t >> 6) & 7;         // per-graph wave
  u32*   F    = Fb + g * (FN * RSW);
  float* s_es = s_scr + g * 1536;
  float* s_ed = s_es + 512;
  float* s_rs = s_es + 1024;
  f32x4 acc[4][2];

  // ================= shared CSR build =================
  int* s_deg  = (int*)s_scr;
  int* s_fill = s_deg + 128;
  const int e_dst = ei[EB + t];
  const int e_src = ei[t];
  if (t < 2 * FN) s_deg[t] = 0;
  __syncthreads();
  atomicAdd(&s_deg[e_dst], 1);

  // ---- input projection + ReLU -> F (packed), per graph
  {
    const int j = u & 127, q = u >> 7;
    const float wv = w_in[j], bv = b_in[j];
    const size_t xb = (size_t)(b * 2 + g) * FN;
    for (int n = q * 32; n < q * 32 + 32; ++n) {
      const float v = fmaxf(fmaf(x[xb + n], wv, bv), 0.f);
      F[n * RSW + j] = pack_hl(v);
    }
  }
  __syncthreads();
  if (t < 64) {                         // wave-0 exclusive scan of (deg+1)
    const int v0 = s_deg[2 * t] + 1, v1 = s_deg[2 * t + 1] + 1;
    const int p = v0 + v1;
    int sc = p;
    #pragma unroll
    for (int off = 1; off < 64; off <<= 1) {
      const int o = __shfl_up(sc, off, 64);
      if (t >= off) sc += o;
    }
    s_rp[2 * t] = sc - p;
    s_rp[2 * t + 1] = sc - v1;
    if (t == 63) s_rp[128] = sc;        // == ET
  } else if (t >= 512 && t < 768) {     // fold BN consts (idle waves)
    const int layer = (t >> 7) & 1;     // 512-639 -> 0, 640-767 -> 1
    const int col = t & 127;
    const float bb = layer ? g1b[col]  : g0b[col];
    const float bm = layer ? bn1m[col] : bn0m[col];
    const float bv = layer ? bn1v[col] : bn0v[col];
    const float bg = layer ? bn1g[col] : bn0g[col];
    const float bt = layer ? bn1b[col] : bn0b[col];
    const float q = bg * rsqrtf(bv + 1e-5f);
    s_bn[layer * 256 + col] = q;
    s_bn[layer * 256 + 128 + col] = (bb - bm) * q + bt;
  }
  __syncthreads();
  {
    const int p = s_rp[e_dst] + atomicAdd(&s_fill[e_dst], 1);
    s_src[p] = e_src | (e_dst << 8);
  }
  if (t < FN) s_src[s_rp[t + 1] - 1] = t | (t << 8);
  __syncthreads();

  // ======================= GAT layer 0 =======================
  mfma_gemm_acc(F, wf, lw, lane, acc);
  __syncthreads();                       // all packed reads done
  store_acc((float*)F, lw, lane, acc);   // F now f32 sg
  __syncthreads();

  // logits per (head, node)
  {
    const int hh = u >> 7, n = u & 127;
    const float* row = (const float*)F + n * RSW + hh * HSZ;
    float accs = 0.f, accd = 0.f;
    #pragma unroll
    for (int s = 0; s < 8; ++s) {
      const int d = ((n + s) & 7) * 4;
      const float4 v  = *(const float4*)(row + d);
      const float4 as = *(const float4*)(g0as + hh * HSZ + d);
      const float4 ad = *(const float4*)(g0ad + hh * HSZ + d);
      accs += v.x*as.x + v.y*as.y + v.z*as.z + v.w*as.w;
      accd += v.x*ad.x + v.y*ad.y + v.z*ad.z + v.w*ad.w;
    }
    s_es[hh * 128 + n] = accs;
    s_ed[hh * 128 + n] = accd;
  }
  __syncthreads();

  // ---- aggregation: thread = (node, head); self-computed sum; 1 exp/edge;
  //      column reads ROTATED by n (bank spread); acc in 32 regs
  {
    const int n = u & 127, hh = u >> 7;
    const int cb = hh * HSZ;
    const float* Ff = (const float*)F;
    const int e0 = s_rp[n], e1 = s_rp[n + 1];
    const float edv = s_ed[hh * 128 + n];
    const float* esb = s_es + hh * 128;
    float sum = 0.f;
    for (int e = e0; e < e1; ++e)
      sum += __expf(lrelu(esb[s_src[e] & 127] + edv));
    const float rsv = 1.f / sum;
    float4 a[8];
    #pragma unroll
    for (int i = 0; i < 8; ++i) a[i] = make_float4(0.f, 0.f, 0.f, 0.f);
    for (int e = e0; e < e1; ++e) {
      const int s = s_src[e] & 127;
      const float al = __expf(lrelu(esb[s] + edv));
      const float* rp_ = Ff + s * RSW + cb;
      #pragma unroll
      for (int i = 0; i < 8; ++i) {
        const int idx = (i + n) & 7;
        const float4 vv = *(const float4*)(rp_ + idx * 4);
        a[idx].x = fmaf(al, vv.x, a[idx].x); a[idx].y = fmaf(al, vv.y, a[idx].y);
        a[idx].z = fmaf(al, vv.z, a[idx].z); a[idx].w = fmaf(al, vv.w, a[idx].w);
      }
    }
    __syncthreads();                     // all sg reads done -> overwrite F
    #pragma unroll
    for (int i = 0; i < 8; ++i) {
      const int col = cb + i * 4;
      const float4 q = *(const float4*)&s_bn[col];
      const float4 r = *(const float4*)&s_bn[128 + col];
      uint4 p;
      p.x = pack_hl(fmaxf(fmaf(a[i].x * rsv, q.x, r.x), 0.f));
      p.y = pack_hl(fmaxf(fmaf(a[i].y * rsv, q.y, r.y), 0.f));
      p.z = pack_hl(fmaxf(fmaf(a[i].z * rsv, q.z, r.z), 0.f));
      p.w = pack_hl(fmaxf(fmaf(a[i].w * rsv, q.w, r.w), 0.f));
      *(uint4*)(F + n * RSW + col) = p;
    }
  }
  __syncthreads();

  // ======================= GAT layer 1 (1 head) =======================
  mfma_gemm_acc(F, wf + 32768, lw, lane, acc);
  __syncthreads();
  store_acc((float*)F, lw, lane, acc);
  __syncthreads();

  // logits partials: 512 threads/graph -> 4 partials per node
  {
    const int n = u >> 2, c = u & 3;
    const float* row = (const float*)F + n * RSW + c * 32;
    float accs = 0.f, accd = 0.f;
    #pragma unroll
    for (int i = 0; i < 8; ++i) {
      const int d = i * 4;
      const float4 v  = *(const float4*)(row + d);
      const float4 as = *(const float4*)(g1as + c * 32 + d);
      const float4 ad = *(const float4*)(g1ad + c * 32 + d);
      accs += v.x*as.x + v.y*as.y + v.z*as.z + v.w*as.w;
      accd += v.x*ad.x + v.y*ad.y + v.z*ad.z + v.w*ad.w;
    }
    s_es[u] = accs;                      // partials [n*4+c]
    s_ed[u] = accd;
  }
  __syncthreads();
  if (u < 128) {                         // combine -> s_rs[n]=es, s_rs[128+n]=ed
    const float* pe = s_es + u * 4;
    const float* pd = s_ed + u * 4;
    s_rs[u]       = pe[0] + pe[1] + pe[2] + pe[3];
    s_rs[128 + u] = pd[0] + pd[1] + pd[2] + pd[3];
  }
  __syncthreads();

  // aggregation layer 1: thread = (node, col-quarter); rotated reads;
  // epilogue stores RAW f32 (pool is the only consumer)
  {
    const int n = u & 127, cg = u >> 7;
    const int cb = cg * HSZ;
    const float* Ff = (const float*)F;
    const int e0 = s_rp[n], e1 = s_rp[n + 1];
    const float edv = s_rs[128 + n];
    float sum = 0.f;
    for (int e = e0; e < e1; ++e)
      sum += __expf(lrelu(s_rs[s_src[e] & 127] + edv));
    const float rsv = 1.f / sum;
    float4 a[8];
    #pragma unroll
    for (int i = 0; i < 8; ++i) a[i] = make_float4(0.f, 0.f, 0.f, 0.f);
    for (int e = e0; e < e1; ++e) {
      const int s = s_src[e] & 127;
      const float al = __expf(lrelu(s_rs[s] + edv));
      const float* rp_ = Ff + s * RSW + cb;
      #pragma unroll
      for (int i = 0; i < 8; ++i) {
        const int idx = (i + n) & 7;
        const float4 vv = *(const float4*)(rp_ + idx * 4);
        a[idx].x = fmaf(al, vv.x, a[idx].x); a[idx].y = fmaf(al, vv.y, a[idx].y);
        a[idx].z = fmaf(al, vv.z, a[idx].z); a[idx].w = fmaf(al, vv.w, a[idx].w);
      }
    }
    __syncthreads();                     // all sg reads done -> overwrite F
    #pragma unroll
    for (int i = 0; i < 8; ++i) {
      const int col = cb + i * 4;
      const float4 q = *(const float4*)&s_bn[256 + col];
      const float4 r = *(const float4*)&s_bn[384 + col];
      uint4 p;
      p.x = __float_as_uint(fmaxf(fmaf(a[i].x * rsv, q.x, r.x), 0.f));
      p.y = __float_as_uint(fmaxf(fmaf(a[i].y * rsv, q.y, r.y), 0.f));
      p.z = __float_as_uint(fmaxf(fmaf(a[i].z * rsv, q.z, r.z), 0.f));
      p.w = __float_as_uint(fmaxf(fmaf(a[i].w * rsv, q.w, r.w), 0.f));
      *(uint4*)(F + n * RSW + col) = p;
    }
  }
  __syncthreads();

  // ---- mean pool (raw f32 in F) + MLP head, per graph
  {
    const int j = u & 127, q = u >> 7;
    float p = 0.f;
    for (int n = q * 32; n < q * 32 + 32; ++n)
      p += __uint_as_float(F[n * RSW + j]);
    s_es[q * 128 + j] = p;
  }
  __syncthreads();
  if (u < 128) {
    s_ed[u] = (s_es[u] + s_es[u + 128] + s_es[u + 256] + s_es[u + 384])
              * (1.f / 128.f);
  }
  __syncthreads();
  {
    const int j = u & 63, part = u >> 6;
    float a = 0.f;
    #pragma unroll
    for (int k = part * 16; k < part * 16 + 16; ++k)
      a = fmaf(s_ed[k], w1[k * 64 + j], a);
    s_rs[part * 64 + j] = a;
  }
  __syncthreads();
  if (u < 64) {
    float a = b1[u];
    #pragma unroll
    for (int p = 0; p < 8; ++p) a += s_rs[p * 64 + u];
    a = fmaxf(a, 0.f);
    float v = a * w2[u];
    #pragma unroll
    for (int off = 32; off > 0; off >>= 1) v += __shfl_down(v, off, 64);
    if (u == 0) out[b * 2 + g] = v + b2[0];
  }
}

extern "C" void kernel_launch(void* const* d_in, const int* in_sizes, int n_in,
                              void* d_out, int out_size, void* d_ws, size_t ws_size,
                              hipStream_t stream)
{
  const float* x    = (const float*)d_in[0];
  const int*   ei   = (const int*)d_in[1];
  const float* w_in = (const float*)d_in[2];
  const float* b_in = (const float*)d_in[3];
  const float* g0w  = (const float*)d_in[4];
  const float* g0as = (const float*)d_in[5];
  const float* g0ad = (const float*)d_in[6];
  const float* g0b  = (const float*)d_in[7];
  const float* bn0g = (const float*)d_in[8];
  const float* bn0b = (const float*)d_in[9];
  const float* bn0m = (const float*)d_in[10];
  const float* bn0v = (const float*)d_in[11];
  const float* g1w  = (const float*)d_in[12];
  const float* g1as = (const float*)d_in[13];
  const float* g1ad = (const float*)d_in[14];
  const float* g1b  = (const float*)d_in[15];
  const float* bn1g = (const float*)d_in[16];
  const float* bn1b = (const float*)d_in[17];
  const float* bn1m = (const float*)d_in[18];
  const float* bn1v = (const float*)d_in[19];
  const float* w1   = (const float*)d_in[20];
  const float* b1   = (const float*)d_in[21];
  const float* w2   = (const float*)d_in[22];
  const float* b2   = (const float*)d_in[23];

  u16* wf = (u16*)d_ws;   // 2 layers x 2 hilo x 16384 bf16 = 128 KB

  prep_w_kernel<<<128, 256, 0, stream>>>(g0w, g1w, wf);
  gnn_fused_kernel<<<512, 1024, 0, stream>>>(x, ei, w_in, b_in,
      g0as, g0ad, g0b, bn0g, bn0b, bn0m, bn0v,
      g1as, g1ad, g1b, bn1g, bn1b, bn1m, bn1v,
      w1, b1, w2, b2, wf, (float*)d_out);
}

// Round 17
// 199.960 us; speedup vs baseline: 8.2879x; 8.2879x over previous
//
#include <hip/hip_runtime.h>

#define FN   128    // nodes per graph
#define HDIM 128    // hidden dim
#define NH   4      // heads, layer 0
#define HSZ  32     // head dim, layer 0
#define EB   1024   // base edges per graph
#define ET   1152   // edges incl. self loops
#define RSW  132    // padded LDS row stride (words)

typedef __attribute__((ext_vector_type(8))) short bf16x8;
typedef __attribute__((ext_vector_type(4))) float f32x4;
typedef unsigned int u32;
typedef unsigned short u16;

union U8 { bf16x8 v; u32 u[4]; };

__device__ __forceinline__ u32 pack_hl(float v) {
  const u32 u = __float_as_uint(v);
  const u32 hib = u & 0xFFFF0000u;
  const float lo = v - __uint_as_float(hib);
  return hib | (__float_as_uint(lo) >> 16);
}
__device__ __forceinline__ float unpack_val(u32 p) {
  return __uint_as_float(p & 0xFFFF0000u) + __uint_as_float(p << 16);
}
__device__ __forceinline__ float lrelu(float v) {
  return (v > 0.f) ? v : 0.2f * v;
}

__device__ __forceinline__ void unpack_frag(const u32* __restrict__ q,
                                            bf16x8& hi, bf16x8& lo)
{
  const uint4 p0 = *(const uint4*)(q);
  const uint4 p1 = *(const uint4*)(q + 4);
  U8 H, L;
  H.u[0] = (p0.x >> 16) | (p0.y & 0xFFFF0000u);
  L.u[0] = (p0.x & 0xFFFFu) | (p0.y << 16);
  H.u[1] = (p0.z >> 16) | (p0.w & 0xFFFF0000u);
  L.u[1] = (p0.z & 0xFFFFu) | (p0.w << 16);
  H.u[2] = (p1.x >> 16) | (p1.y & 0xFFFF0000u);
  L.u[2] = (p1.x & 0xFFFFu) | (p1.y << 16);
  H.u[3] = (p1.z >> 16) | (p1.w & 0xFFFF0000u);
  L.u[3] = (p1.z & 0xFFFFu) | (p1.w << 16);
  hi = H.v; lo = L.v;
}

// ---------------- W -> split bf16 hi/lo, B-fragment layout (r3-verified) ----
__global__ __launch_bounds__(256) void prep_w_kernel(
    const float* __restrict__ g0w, const float* __restrict__ g1w,
    u16* __restrict__ wf)
{
  const int idx = blockIdx.x * 256 + threadIdx.x;   // 32768 total
  const int layer = idx >> 14;
  const int r = idx & 16383;
  const int c  = r >> 11;
  const int kc = (r >> 9) & 3;
  const int l  = (r >> 3) & 63;
  const int j  = r & 7;
  const int k = kc * 32 + (l >> 4) * 8 + j;
  const int n = c * 16 + (l & 15);
  const float* W = layer ? g1w : g0w;
  const float v = W[k * HDIM + n];
  const u32 u = __float_as_uint(v);
  const u32 hib = u & 0xFFFF0000u;
  const float lo = v - __uint_as_float(hib);
  wf[layer * 32768 + r]         = (u16)(u >> 16);
  wf[layer * 32768 + 16384 + r] = (u16)(__float_as_uint(lo) >> 16);
}

// MFMA GEMM, 8 waves/graph (r12/r14-verified): wave tile 32 cols x 64 rows.
__device__ __forceinline__ void mfma_gemm_acc(const u32* __restrict__ F,
                                              const u16* __restrict__ wf,
                                              int lw, int lane, f32x4 acc[4][2])
{
  const int cg = lw & 3, rh = lw >> 2;
  const int m = lane & 15, quad = lane >> 4;

  #pragma unroll
  for (int s = 0; s < 4; ++s)
    #pragma unroll
    for (int ct = 0; ct < 2; ++ct) acc[s][ct] = (f32x4){0.f, 0.f, 0.f, 0.f};

  const u16* bbase = wf + (cg * 8) * 512 + lane * 8;   // ct +2048, kc +512

  #pragma unroll
  for (int kc = 0; kc < 4; ++kc) {
    bf16x8 bhi[2], blo[2];
    #pragma unroll
    for (int ct = 0; ct < 2; ++ct) {
      const u16* bp = bbase + ct * 2048 + kc * 512;
      bhi[ct] = *(const bf16x8*)bp;
      blo[ct] = *(const bf16x8*)(bp + 16384);
    }
    #pragma unroll
    for (int s = 0; s < 4; ++s) {
      const u32* ap = F + (rh * 64 + s * 16 + m) * RSW + quad * 8 + kc * 32;
      bf16x8 ahi, alo;
      unpack_frag(ap, ahi, alo);
      #pragma unroll
      for (int ct = 0; ct < 2; ++ct) {
        acc[s][ct] = __builtin_amdgcn_mfma_f32_16x16x32_bf16(ahi, bhi[ct], acc[s][ct], 0, 0, 0);
        acc[s][ct] = __builtin_amdgcn_mfma_f32_16x16x32_bf16(alo, bhi[ct], acc[s][ct], 0, 0, 0);
        acc[s][ct] = __builtin_amdgcn_mfma_f32_16x16x32_bf16(ahi, blo[ct], acc[s][ct], 0, 0, 0);
      }
    }
  }
}

// store acc -> plain f32 (in-place into F); C/D: col = lane&15, row = quad*4+r
__device__ __forceinline__ void store_acc(float* __restrict__ sg, int lw,
                                          int lane, const f32x4 acc[4][2])
{
  const int cg = lw & 3, rh = lw >> 2;
  const int m = lane & 15, quad = lane >> 4;
  #pragma unroll
  for (int s = 0; s < 4; ++s) {
    const int row0 = rh * 64 + s * 16 + quad * 4;
    #pragma unroll
    for (int ct = 0; ct < 2; ++ct)
      #pragma unroll
      for (int r = 0; r < 4; ++r)
        sg[(row0 + r) * RSW + cg * 32 + ct * 16 + m] = acc[s][ct][r];
  }
}

// ---------------- fused GNN: 1024 threads, TWO graphs per block ------------
__global__ __launch_bounds__(1024) void gnn_fused_kernel(
    const float* __restrict__ x, const int* __restrict__ ei,
    const float* __restrict__ w_in, const float* __restrict__ b_in,
    const float* __restrict__ g0as, const float* __restrict__ g0ad,
    const float* __restrict__ g0b,
    const float* __restrict__ bn0g, const float* __restrict__ bn0b,
    const float* __restrict__ bn0m, const float* __restrict__ bn0v,
    const float* __restrict__ g1as, const float* __restrict__ g1ad,
    const float* __restrict__ g1b,
    const float* __restrict__ bn1g, const float* __restrict__ bn1b,
    const float* __restrict__ bn1m, const float* __restrict__ bn1v,
    const float* __restrict__ w1, const float* __restrict__ b1,
    const float* __restrict__ w2, const float* __restrict__ b2,
    const u16* __restrict__ wf,
    float* __restrict__ out)
{
  __shared__ u32   Fb[2 * FN * RSW];   // 135168 B: per-graph packed feat <-> f32 sg
  __shared__ int   s_src[ET];          // src | dst<<8 (SHARED topology)
  __shared__ int   s_rp[FN + 1];
  __shared__ float s_scr[3072];        // per graph: es 512 | ed 512 | rs 512
  __shared__ float s_bn[512];          // folded BN consts: [l*256 + {q:0,r:128} + col]

  const int t = threadIdx.x;
  const int b = blockIdx.x;
  const int g = t >> 9;                // graph within block
  const int u = t & 511;               // per-graph thread
  const int lane = t & 63;
  const int lw = (t >> 6) & 7;         // per-graph wave
  u32*   F    = Fb + g * (FN * RSW);
  float* s_es = s_scr + g * 1536;
  float* s_ed = s_es + 512;
  float* s_rs = s_es + 1024;
  f32x4 acc[4][2];

  // ================= shared CSR build =================
  int* s_deg  = (int*)s_scr;
  int* s_fill = s_deg + 128;
  const int e_dst = ei[EB + t];
  const int e_src = ei[t];
  if (t < 2 * FN) s_deg[t] = 0;
  __syncthreads();
  atomicAdd(&s_deg[e_dst], 1);

  // ---- input projection + ReLU -> F (packed), per graph
  {
    const int j = u & 127, q = u >> 7;
    const float wv = w_in[j], bv = b_in[j];
    const size_t xb = (size_t)(b * 2 + g) * FN;
    for (int n = q * 32; n < q * 32 + 32; ++n) {
      const float v = fmaxf(fmaf(x[xb + n], wv, bv), 0.f);
      F[n * RSW + j] = pack_hl(v);
    }
  }
  __syncthreads();
  if (t < 64) {                         // wave-0 exclusive scan of (deg+1)
    const int v0 = s_deg[2 * t] + 1, v1 = s_deg[2 * t + 1] + 1;
    const int p = v0 + v1;
    int sc = p;
    #pragma unroll
    for (int off = 1; off < 64; off <<= 1) {
      const int o = __shfl_up(sc, off, 64);
      if (t >= off) sc += o;
    }
    s_rp[2 * t] = sc - p;
    s_rp[2 * t + 1] = sc - v1;
    if (t == 63) s_rp[128] = sc;        // == ET
  } else if (t >= 512 && t < 768) {     // fold BN consts (idle waves)
    const int layer = (t >> 7) & 1;     // 512-639 -> 0, 640-767 -> 1
    const int col = t & 127;
    const float bb = layer ? g1b[col]  : g0b[col];
    const float bm = layer ? bn1m[col] : bn0m[col];
    const float bv = layer ? bn1v[col] : bn0v[col];
    const float bg = layer ? bn1g[col] : bn0g[col];
    const float bt = layer ? bn1b[col] : bn0b[col];
    const float q = bg * rsqrtf(bv + 1e-5f);
    s_bn[layer * 256 + col] = q;
    s_bn[layer * 256 + 128 + col] = (bb - bm) * q + bt;
  }
  __syncthreads();
  {
    const int p = s_rp[e_dst] + atomicAdd(&s_fill[e_dst], 1);
    s_src[p] = e_src | (e_dst << 8);
  }
  if (t < FN) s_src[s_rp[t + 1] - 1] = t | (t << 8);
  __syncthreads();

  // ======================= GAT layer 0 =======================
  mfma_gemm_acc(F, wf, lw, lane, acc);
  __syncthreads();                       // all packed reads done
  store_acc((float*)F, lw, lane, acc);   // F now f32 sg
  __syncthreads();

  // logits per (head, node)
  {
    const int hh = u >> 7, n = u & 127;
    const float* row = (const float*)F + n * RSW + hh * HSZ;
    float accs = 0.f, accd = 0.f;
    #pragma unroll
    for (int s = 0; s < 8; ++s) {
      const int d = ((n + s) & 7) * 4;
      const float4 v  = *(const float4*)(row + d);
      const float4 as = *(const float4*)(g0as + hh * HSZ + d);
      const float4 ad = *(const float4*)(g0ad + hh * HSZ + d);
      accs += v.x*as.x + v.y*as.y + v.z*as.z + v.w*as.w;
      accd += v.x*ad.x + v.y*ad.y + v.z*ad.z + v.w*ad.w;
    }
    s_es[hh * 128 + n] = accs;
    s_ed[hh * 128 + n] = accd;
  }
  __syncthreads();

  // ---- aggregation: thread = (node, head); self-computed sum; 1 exp/edge.
  //      Rotation via PER-THREAD CONSTANT offset: a[i] owns logical column
  //      (i+off)&7 — all accumulator indices are compile-time (no spill).
  {
    const int n = u & 127, hh = u >> 7;
    const int cb = hh * HSZ;
    const int off = n & 7;
    const float* Ff = (const float*)F;
    const int e0 = s_rp[n], e1 = s_rp[n + 1];
    const float edv = s_ed[hh * 128 + n];
    const float* esb = s_es + hh * 128;
    float sum = 0.f;
    for (int e = e0; e < e1; ++e)
      sum += __expf(lrelu(esb[s_src[e] & 127] + edv));
    const float rsv = 1.f / sum;
    float4 a[8];
    #pragma unroll
    for (int i = 0; i < 8; ++i) a[i] = make_float4(0.f, 0.f, 0.f, 0.f);
    for (int e = e0; e < e1; ++e) {
      const int s = s_src[e] & 127;
      const float al = __expf(lrelu(esb[s] + edv));
      const float* rp_ = Ff + s * RSW + cb;
      #pragma unroll
      for (int i = 0; i < 8; ++i) {
        const float4 vv = *(const float4*)(rp_ + ((i + off) & 7) * 4);
        a[i].x = fmaf(al, vv.x, a[i].x); a[i].y = fmaf(al, vv.y, a[i].y);
        a[i].z = fmaf(al, vv.z, a[i].z); a[i].w = fmaf(al, vv.w, a[i].w);
      }
    }
    __syncthreads();                     // all sg reads done -> overwrite F
    #pragma unroll
    for (int i = 0; i < 8; ++i) {
      const int col = cb + ((i + off) & 7) * 4;
      const float4 q = *(const float4*)&s_bn[col];
      const float4 r = *(const float4*)&s_bn[128 + col];
      uint4 p;
      p.x = pack_hl(fmaxf(fmaf(a[i].x * rsv, q.x, r.x), 0.f));
      p.y = pack_hl(fmaxf(fmaf(a[i].y * rsv, q.y, r.y), 0.f));
      p.z = pack_hl(fmaxf(fmaf(a[i].z * rsv, q.z, r.z), 0.f));
      p.w = pack_hl(fmaxf(fmaf(a[i].w * rsv, q.w, r.w), 0.f));
      *(uint4*)(F + n * RSW + col) = p;
    }
  }
  __syncthreads();

  // ======================= GAT layer 1 (1 head) =======================
  mfma_gemm_acc(F, wf + 32768, lw, lane, acc);
  __syncthreads();
  store_acc((float*)F, lw, lane, acc);
  __syncthreads();

  // logits partials: 512 threads/graph -> 4 partials per node
  {
    const int n = u >> 2, c = u & 3;
    const float* row = (const float*)F + n * RSW + c * 32;
    float accs = 0.f, accd = 0.f;
    #pragma unroll
    for (int i = 0; i < 8; ++i) {
      const int d = i * 4;
      const float4 v  = *(const float4*)(row + d);
      const float4 as = *(const float4*)(g1as + c * 32 + d);
      const float4 ad = *(const float4*)(g1ad + c * 32 + d);
      accs += v.x*as.x + v.y*as.y + v.z*as.z + v.w*as.w;
      accd += v.x*ad.x + v.y*ad.y + v.z*ad.z + v.w*ad.w;
    }
    s_es[u] = accs;                      // partials [n*4+c]
    s_ed[u] = accd;
  }
  __syncthreads();
  if (u < 128) {                         // combine -> s_rs[n]=es, s_rs[128+n]=ed
    const float* pe = s_es + u * 4;
    const float* pd = s_ed + u * 4;
    s_rs[u]       = pe[0] + pe[1] + pe[2] + pe[3];
    s_rs[128 + u] = pd[0] + pd[1] + pd[2] + pd[3];
  }
  __syncthreads();

  // aggregation layer 1: thread = (node, col-quarter); constant-offset
  // rotation; epilogue stores RAW f32 (pool is the only consumer)
  {
    const int n = u & 127, cg = u >> 7;
    const int cb = cg * HSZ;
    const int off = n & 7;
    const float* Ff = (const float*)F;
    const int e0 = s_rp[n], e1 = s_rp[n + 1];
    const float edv = s_rs[128 + n];
    float sum = 0.f;
    for (int e = e0; e < e1; ++e)
      sum += __expf(lrelu(s_rs[s_src[e] & 127] + edv));
    const float rsv = 1.f / sum;
    float4 a[8];
    #pragma unroll
    for (int i = 0; i < 8; ++i) a[i] = make_float4(0.f, 0.f, 0.f, 0.f);
    for (int e = e0; e < e1; ++e) {
      const int s = s_src[e] & 127;
      const float al = __expf(lrelu(s_rs[s] + edv));
      const float* rp_ = Ff + s * RSW + cb;
      #pragma unroll
      for (int i = 0; i < 8; ++i) {
        const float4 vv = *(const float4*)(rp_ + ((i + off) & 7) * 4);
        a[i].x = fmaf(al, vv.x, a[i].x); a[i].y = fmaf(al, vv.y, a[i].y);
        a[i].z = fmaf(al, vv.z, a[i].z); a[i].w = fmaf(al, vv.w, a[i].w);
      }
    }
    __syncthreads();                     // all sg reads done -> overwrite F
    #pragma unroll
    for (int i = 0; i < 8; ++i) {
      const int col = cb + ((i + off) & 7) * 4;
      const float4 q = *(const float4*)&s_bn[256 + col];
      const float4 r = *(const float4*)&s_bn[384 + col];
      uint4 p;
      p.x = __float_as_uint(fmaxf(fmaf(a[i].x * rsv, q.x, r.x), 0.f));
      p.y = __float_as_uint(fmaxf(fmaf(a[i].y * rsv, q.y, r.y), 0.f));
      p.z = __float_as_uint(fmaxf(fmaf(a[i].z * rsv, q.z, r.z), 0.f));
      p.w = __float_as_uint(fmaxf(fmaf(a[i].w * rsv, q.w, r.w), 0.f));
      *(uint4*)(F + n * RSW + col) = p;
    }
  }
  __syncthreads();

  // ---- mean pool (raw f32 in F) + MLP head, per graph
  {
    const int j = u & 127, q = u >> 7;
    float p = 0.f;
    for (int n = q * 32; n < q * 32 + 32; ++n)
      p += __uint_as_float(F[n * RSW + j]);
    s_es[q * 128 + j] = p;
  }
  __syncthreads();
  if (u < 128) {
    s_ed[u] = (s_es[u] + s_es[u + 128] + s_es[u + 256] + s_es[u + 384])
              * (1.f / 128.f);
  }
  __syncthreads();
  {
    const int j = u & 63, part = u >> 6;
    float a = 0.f;
    #pragma unroll
    for (int k = part * 16; k < part * 16 + 16; ++k)
      a = fmaf(s_ed[k], w1[k * 64 + j], a);
    s_rs[part * 64 + j] = a;
  }
  __syncthreads();
  if (u < 64) {
    float a = b1[u];
    #pragma unroll
    for (int p = 0; p < 8; ++p) a += s_rs[p * 64 + u];
    a = fmaxf(a, 0.f);
    float v = a * w2[u];
    #pragma unroll
    for (int off = 32; off > 0; off >>= 1) v += __shfl_down(v, off, 64);
    if (u == 0) out[b * 2 + g] = v + b2[0];
  }
}

extern "C" void kernel_launch(void* const* d_in, const int* in_sizes, int n_in,
                              void* d_out, int out_size, void* d_ws, size_t ws_size,
                              hipStream_t stream)
{
  const float* x    = (const float*)d_in[0];
  const int*   ei   = (const int*)d_in[1];
  const float* w_in = (const float*)d_in[2];
  const float* b_in = (const float*)d_in[3];
  const float* g0w  = (const float*)d_in[4];
  const float* g0as = (const float*)d_in[5];
  const float* g0ad = (const float*)d_in[6];
  const float* g0b  = (const float*)d_in[7];
  const float* bn0g = (const float*)d_in[8];
  const float* bn0b = (const float*)d_in[9];
  const float* bn0m = (const float*)d_in[10];
  const float* bn0v = (const float*)d_in[11];
  const float* g1w  = (const float*)d_in[12];
  const float* g1as = (const float*)d_in[13];
  const float* g1ad = (const float*)d_in[14];
  const float* g1b  = (const float*)d_in[15];
  const float* bn1g = (const float*)d_in[16];
  const float* bn1b = (const float*)d_in[17];
  const float* bn1m = (const float*)d_in[18];
  const float* bn1v = (const float*)d_in[19];
  const float* w1   = (const float*)d_in[20];
  const float* b1   = (const float*)d_in[21];
  const float* w2   = (const float*)d_in[22];
  const float* b2   = (const float*)d_in[23];

  u16* wf = (u16*)d_ws;   // 2 layers x 2 hilo x 16384 bf16 = 128 KB

  prep_w_kernel<<<128, 256, 0, stream>>>(g0w, g1w, wf);
  gnn_fused_kernel<<<512, 1024, 0, stream>>>(x, ei, w_in, b_in,
      g0as, g0ad, g0b, bn0g, bn0b, bn0m, bn0v,
      g1as, g1ad, g1b, bn1g, bn1b, bn1m, bn1v,
      w1, b1, w2, b2, wf, (float*)d_out);
}

// Round 18
// 190.396 us; speedup vs baseline: 8.7043x; 1.0502x over previous
//
#include <hip/hip_runtime.h>

#define FN   128    // nodes per graph
#define HDIM 128    // hidden dim
#define NH   4      // heads, layer 0
#define HSZ  32     // head dim, layer 0
#define EB   1024   // base edges per graph
#define ET   1152   // edges incl. self loops
#define RSW  132    // padded LDS row stride (words)

typedef __attribute__((ext_vector_type(8))) short bf16x8;
typedef __attribute__((ext_vector_type(4))) float f32x4;
typedef unsigned int u32;
typedef unsigned short u16;

union U8 { bf16x8 v; u32 u[4]; };

__device__ __forceinline__ u32 pack_hl(float v) {
  const u32 u = __float_as_uint(v);
  const u32 hib = u & 0xFFFF0000u;
  const float lo = v - __uint_as_float(hib);
  return hib | (__float_as_uint(lo) >> 16);
}
__device__ __forceinline__ float unpack_val(u32 p) {
  return __uint_as_float(p & 0xFFFF0000u) + __uint_as_float(p << 16);
}
__device__ __forceinline__ float lrelu(float v) {
  return (v > 0.f) ? v : 0.2f * v;
}

__device__ __forceinline__ void unpack_frag(const u32* __restrict__ q,
                                            bf16x8& hi, bf16x8& lo)
{
  const uint4 p0 = *(const uint4*)(q);
  const uint4 p1 = *(const uint4*)(q + 4);
  U8 H, L;
  H.u[0] = (p0.x >> 16) | (p0.y & 0xFFFF0000u);
  L.u[0] = (p0.x & 0xFFFFu) | (p0.y << 16);
  H.u[1] = (p0.z >> 16) | (p0.w & 0xFFFF0000u);
  L.u[1] = (p0.z & 0xFFFFu) | (p0.w << 16);
  H.u[2] = (p1.x >> 16) | (p1.y & 0xFFFF0000u);
  L.u[2] = (p1.x & 0xFFFFu) | (p1.y << 16);
  H.u[3] = (p1.z >> 16) | (p1.w & 0xFFFF0000u);
  L.u[3] = (p1.z & 0xFFFFu) | (p1.w << 16);
  hi = H.v; lo = L.v;
}

// ---------------- W -> split bf16 hi/lo, B-fragment layout (r3-verified) ----
__global__ __launch_bounds__(256) void prep_w_kernel(
    const float* __restrict__ g0w, const float* __restrict__ g1w,
    u16* __restrict__ wf)
{
  const int idx = blockIdx.x * 256 + threadIdx.x;   // 32768 total
  const int layer = idx >> 14;
  const int r = idx & 16383;
  const int c  = r >> 11;
  const int kc = (r >> 9) & 3;
  const int l  = (r >> 3) & 63;
  const int j  = r & 7;
  const int k = kc * 32 + (l >> 4) * 8 + j;
  const int n = c * 16 + (l & 15);
  const float* W = layer ? g1w : g0w;
  const float v = W[k * HDIM + n];
  const u32 u = __float_as_uint(v);
  const u32 hib = u & 0xFFFF0000u;
  const float lo = v - __uint_as_float(hib);
  wf[layer * 32768 + r]         = (u16)(u >> 16);
  wf[layer * 32768 + 16384 + r] = (u16)(__float_as_uint(lo) >> 16);
}

// MFMA GEMM, 8 waves/graph (r12/r14-verified): wave tile 32 cols x 64 rows.
__device__ __forceinline__ void mfma_gemm_acc(const u32* __restrict__ F,
                                              const u16* __restrict__ wf,
                                              int lw, int lane, f32x4 acc[4][2])
{
  const int cg = lw & 3, rh = lw >> 2;
  const int m = lane & 15, quad = lane >> 4;

  #pragma unroll
  for (int s = 0; s < 4; ++s)
    #pragma unroll
    for (int ct = 0; ct < 2; ++ct) acc[s][ct] = (f32x4){0.f, 0.f, 0.f, 0.f};

  const u16* bbase = wf + (cg * 8) * 512 + lane * 8;   // ct +2048, kc +512

  #pragma unroll
  for (int kc = 0; kc < 4; ++kc) {
    bf16x8 bhi[2], blo[2];
    #pragma unroll
    for (int ct = 0; ct < 2; ++ct) {
      const u16* bp = bbase + ct * 2048 + kc * 512;
      bhi[ct] = *(const bf16x8*)bp;
      blo[ct] = *(const bf16x8*)(bp + 16384);
    }
    #pragma unroll
    for (int s = 0; s < 4; ++s) {
      const u32* ap = F + (rh * 64 + s * 16 + m) * RSW + quad * 8 + kc * 32;
      bf16x8 ahi, alo;
      unpack_frag(ap, ahi, alo);
      #pragma unroll
      for (int ct = 0; ct < 2; ++ct) {
        acc[s][ct] = __builtin_amdgcn_mfma_f32_16x16x32_bf16(ahi, bhi[ct], acc[s][ct], 0, 0, 0);
        acc[s][ct] = __builtin_amdgcn_mfma_f32_16x16x32_bf16(alo, bhi[ct], acc[s][ct], 0, 0, 0);
        acc[s][ct] = __builtin_amdgcn_mfma_f32_16x16x32_bf16(ahi, blo[ct], acc[s][ct], 0, 0, 0);
      }
    }
  }
}

// store acc -> plain f32 (in-place into F); C/D: col = lane&15, row = quad*4+r
__device__ __forceinline__ void store_acc(float* __restrict__ sg, int lw,
                                          int lane, const f32x4 acc[4][2])
{
  const int cg = lw & 3, rh = lw >> 2;
  const int m = lane & 15, quad = lane >> 4;
  #pragma unroll
  for (int s = 0; s < 4; ++s) {
    const int row0 = rh * 64 + s * 16 + quad * 4;
    #pragma unroll
    for (int ct = 0; ct < 2; ++ct)
      #pragma unroll
      for (int r = 0; r < 4; ++r)
        sg[(row0 + r) * RSW + cg * 32 + ct * 16 + m] = acc[s][ct][r];
  }
}

// ---------------- fused GNN: 1024 threads, TWO graphs per block ------------
__global__ __launch_bounds__(1024) void gnn_fused_kernel(
    const float* __restrict__ x, const int* __restrict__ ei,
    const float* __restrict__ w_in, const float* __restrict__ b_in,
    const float* __restrict__ g0as, const float* __restrict__ g0ad,
    const float* __restrict__ g0b,
    const float* __restrict__ bn0g, const float* __restrict__ bn0b,
    const float* __restrict__ bn0m, const float* __restrict__ bn0v,
    const float* __restrict__ g1as, const float* __restrict__ g1ad,
    const float* __restrict__ g1b,
    const float* __restrict__ bn1g, const float* __restrict__ bn1b,
    const float* __restrict__ bn1m, const float* __restrict__ bn1v,
    const float* __restrict__ w1, const float* __restrict__ b1,
    const float* __restrict__ w2, const float* __restrict__ b2,
    const u16* __restrict__ wf,
    float* __restrict__ out)
{
  __shared__ u32   Fb[2 * FN * RSW];   // 135168 B: per-graph packed feat <-> f32 sg
  __shared__ int   s_src[ET];          // src | dst<<8 (SHARED topology)
  __shared__ int   s_rp[FN + 1];
  __shared__ float s_scr[3072];        // per graph: es 512 | ed 512 | rs 512
  __shared__ float s_bn[512];          // folded BN consts: [l*256 + {q:0,r:128} + col]

  const int t = threadIdx.x;
  const int b = blockIdx.x;
  const int g = t >> 9;                // graph within block
  const int u = t & 511;               // per-graph thread
  const int lane = t & 63;
  const int lw = (t >> 6) & 7;         // per-graph wave
  u32*   F    = Fb + g * (FN * RSW);
  float* s_es = s_scr + g * 1536;
  float* s_ed = s_es + 512;
  float* s_rs = s_es + 1024;
  f32x4 acc[4][2];

  // ================= shared CSR build =================
  int* s_deg  = (int*)s_scr;
  int* s_fill = s_deg + 128;
  const int e_dst = ei[EB + t];
  const int e_src = ei[t];
  if (t < 2 * FN) s_deg[t] = 0;
  __syncthreads();
  atomicAdd(&s_deg[e_dst], 1);

  // ---- input projection + ReLU -> F (packed), per graph
  {
    const int j = u & 127, q = u >> 7;
    const float wv = w_in[j], bv = b_in[j];
    const size_t xb = (size_t)(b * 2 + g) * FN;
    for (int n = q * 32; n < q * 32 + 32; ++n) {
      const float v = fmaxf(fmaf(x[xb + n], wv, bv), 0.f);
      F[n * RSW + j] = pack_hl(v);
    }
  }
  __syncthreads();
  if (t < 64) {                         // wave-0 exclusive scan of (deg+1)
    const int v0 = s_deg[2 * t] + 1, v1 = s_deg[2 * t + 1] + 1;
    const int p = v0 + v1;
    int sc = p;
    #pragma unroll
    for (int off = 1; off < 64; off <<= 1) {
      const int o = __shfl_up(sc, off, 64);
      if (t >= off) sc += o;
    }
    s_rp[2 * t] = sc - p;
    s_rp[2 * t + 1] = sc - v1;
    if (t == 63) s_rp[128] = sc;        // == ET
  } else if (t >= 512 && t < 768) {     // fold BN consts (idle waves)
    const int layer = (t >> 7) & 1;     // 512-639 -> 0, 640-767 -> 1
    const int col = t & 127;
    const float bb = layer ? g1b[col]  : g0b[col];
    const float bm = layer ? bn1m[col] : bn0m[col];
    const float bv = layer ? bn1v[col] : bn0v[col];
    const float bg = layer ? bn1g[col] : bn0g[col];
    const float bt = layer ? bn1b[col] : bn0b[col];
    const float q = bg * rsqrtf(bv + 1e-5f);
    s_bn[layer * 256 + col] = q;
    s_bn[layer * 256 + 128 + col] = (bb - bm) * q + bt;
  }
  __syncthreads();
  {
    const int p = s_rp[e_dst] + atomicAdd(&s_fill[e_dst], 1);
    s_src[p] = e_src | (e_dst << 8);
  }
  if (t < FN) s_src[s_rp[t + 1] - 1] = t | (t << 8);
  __syncthreads();

  // ======================= GAT layer 0 =======================
  mfma_gemm_acc(F, wf, lw, lane, acc);
  __syncthreads();                       // all packed reads done
  store_acc((float*)F, lw, lane, acc);   // F now f32 sg
  __syncthreads();

  // logits per (head, node)
  {
    const int hh = u >> 7, n = u & 127;
    const float* row = (const float*)F + n * RSW + hh * HSZ;
    float accs = 0.f, accd = 0.f;
    #pragma unroll
    for (int s = 0; s < 8; ++s) {
      const int d = ((n + s) & 7) * 4;
      const float4 v  = *(const float4*)(row + d);
      const float4 as = *(const float4*)(g0as + hh * HSZ + d);
      const float4 ad = *(const float4*)(g0ad + hh * HSZ + d);
      accs += v.x*as.x + v.y*as.y + v.z*as.z + v.w*as.w;
      accd += v.x*ad.x + v.y*ad.y + v.z*ad.z + v.w*ad.w;
    }
    s_es[hh * 128 + n] = accs;
    s_ed[hh * 128 + n] = accd;
  }
  __syncthreads();

  // ---- aggregation: thread = (node, head); self-computed sum; 1 exp/edge;
  //      acc in 32 regs across in-place barrier (r15-verified)
  {
    const int n = u & 127, hh = u >> 7;
    const int cb = hh * HSZ;
    const float* Ff = (const float*)F;
    const int e0 = s_rp[n], e1 = s_rp[n + 1];
    const float edv = s_ed[hh * 128 + n];
    const float* esb = s_es + hh * 128;
    float sum = 0.f;
    for (int e = e0; e < e1; ++e)
      sum += __expf(lrelu(esb[s_src[e] & 127] + edv));
    const float rsv = 1.f / sum;
    float4 a[8];
    #pragma unroll
    for (int i = 0; i < 8; ++i) a[i] = make_float4(0.f, 0.f, 0.f, 0.f);
    for (int e = e0; e < e1; ++e) {
      const int s = s_src[e] & 127;
      const float al = __expf(lrelu(esb[s] + edv));
      const float* rp_ = Ff + s * RSW + cb;
      #pragma unroll
      for (int i = 0; i < 8; ++i) {
        const float4 vv = *(const float4*)(rp_ + i * 4);
        a[i].x = fmaf(al, vv.x, a[i].x); a[i].y = fmaf(al, vv.y, a[i].y);
        a[i].z = fmaf(al, vv.z, a[i].z); a[i].w = fmaf(al, vv.w, a[i].w);
      }
    }
    __syncthreads();                     // all sg reads done -> overwrite F
    #pragma unroll
    for (int i = 0; i < 8; ++i) {
      const int col = cb + i * 4;
      const float4 q = *(const float4*)&s_bn[col];
      const float4 r = *(const float4*)&s_bn[128 + col];
      uint4 p;
      p.x = pack_hl(fmaxf(fmaf(a[i].x * rsv, q.x, r.x), 0.f));
      p.y = pack_hl(fmaxf(fmaf(a[i].y * rsv, q.y, r.y), 0.f));
      p.z = pack_hl(fmaxf(fmaf(a[i].z * rsv, q.z, r.z), 0.f));
      p.w = pack_hl(fmaxf(fmaf(a[i].w * rsv, q.w, r.w), 0.f));
      *(uint4*)(F + n * RSW + col) = p;
    }
  }
  __syncthreads();

  // ======================= GAT layer 1 (1 head) =======================
  mfma_gemm_acc(F, wf + 32768, lw, lane, acc);
  __syncthreads();
  store_acc((float*)F, lw, lane, acc);
  __syncthreads();

  // logits partials: 512 threads/graph -> 4 partials per node
  {
    const int n = u >> 2, c = u & 3;
    const float* row = (const float*)F + n * RSW + c * 32;
    float accs = 0.f, accd = 0.f;
    #pragma unroll
    for (int i = 0; i < 8; ++i) {
      const int d = i * 4;
      const float4 v  = *(const float4*)(row + d);
      const float4 as = *(const float4*)(g1as + c * 32 + d);
      const float4 ad = *(const float4*)(g1ad + c * 32 + d);
      accs += v.x*as.x + v.y*as.y + v.z*as.z + v.w*as.w;
      accd += v.x*ad.x + v.y*ad.y + v.z*ad.z + v.w*ad.w;
    }
    s_es[u] = accs;                      // partials [n*4+c]
    s_ed[u] = accd;
  }
  __syncthreads();
  if (u < 128) {                         // combine -> s_rs[n]=es, s_rs[128+n]=ed
    const float* pe = s_es + u * 4;
    const float* pd = s_ed + u * 4;
    s_rs[u]       = pe[0] + pe[1] + pe[2] + pe[3];
    s_rs[128 + u] = pd[0] + pd[1] + pd[2] + pd[3];
  }
  __syncthreads();

  // aggregation layer 1: thread = (node, col-quarter); self-computed sum;
  // epilogue stores RAW f32 (pool is the only consumer)
  {
    const int n = u & 127, cg = u >> 7;
    const int cb = cg * HSZ;
    const float* Ff = (const float*)F;
    const int e0 = s_rp[n], e1 = s_rp[n + 1];
    const float edv = s_rs[128 + n];
    float sum = 0.f;
    for (int e = e0; e < e1; ++e)
      sum += __expf(lrelu(s_rs[s_src[e] & 127] + edv));
    const float rsv = 1.f / sum;
    float4 a[8];
    #pragma unroll
    for (int i = 0; i < 8; ++i) a[i] = make_float4(0.f, 0.f, 0.f, 0.f);
    for (int e = e0; e < e1; ++e) {
      const int s = s_src[e] & 127;
      const float al = __expf(lrelu(s_rs[s] + edv));
      const float* rp_ = Ff + s * RSW + cb;
      #pragma unroll
      for (int i = 0; i < 8; ++i) {
        const float4 vv = *(const float4*)(rp_ + i * 4);
        a[i].x = fmaf(al, vv.x, a[i].x); a[i].y = fmaf(al, vv.y, a[i].y);
        a[i].z = fmaf(al, vv.z, a[i].z); a[i].w = fmaf(al, vv.w, a[i].w);
      }
    }
    __syncthreads();                     // all sg reads done -> overwrite F
    #pragma unroll
    for (int i = 0; i < 8; ++i) {
      const int col = cb + i * 4;
      const float4 q = *(const float4*)&s_bn[256 + col];
      const float4 r = *(const float4*)&s_bn[384 + col];
      uint4 p;
      p.x = __float_as_uint(fmaxf(fmaf(a[i].x * rsv, q.x, r.x), 0.f));
      p.y = __float_as_uint(fmaxf(fmaf(a[i].y * rsv, q.y, r.y), 0.f));
      p.z = __float_as_uint(fmaxf(fmaf(a[i].z * rsv, q.z, r.z), 0.f));
      p.w = __float_as_uint(fmaxf(fmaf(a[i].w * rsv, q.w, r.w), 0.f));
      *(uint4*)(F + n * RSW + col) = p;
    }
  }
  __syncthreads();

  // ---- mean pool (raw f32 in F) + MLP head, per graph
  {
    const int j = u & 127, q = u >> 7;
    float p = 0.f;
    for (int n = q * 32; n < q * 32 + 32; ++n)
      p += __uint_as_float(F[n * RSW + j]);
    s_es[q * 128 + j] = p;
  }
  __syncthreads();
  if (u < 128) {
    s_ed[u] = (s_es[u] + s_es[u + 128] + s_es[u + 256] + s_es[u + 384])
              * (1.f / 128.f);
  }
  __syncthreads();
  {
    const int j = u & 63, part = u >> 6;
    float a = 0.f;
    #pragma unroll
    for (int k = part * 16; k < part * 16 + 16; ++k)
      a = fmaf(s_ed[k], w1[k * 64 + j], a);
    s_rs[part * 64 + j] = a;
  }
  __syncthreads();
  if (u < 64) {
    float a = b1[u];
    #pragma unroll
    for (int p = 0; p < 8; ++p) a += s_rs[p * 64 + u];
    a = fmaxf(a, 0.f);
    float v = a * w2[u];
    #pragma unroll
    for (int off = 32; off > 0; off >>= 1) v += __shfl_down(v, off, 64);
    if (u == 0) out[b * 2 + g] = v + b2[0];
  }
}

extern "C" void kernel_launch(void* const* d_in, const int* in_sizes, int n_in,
                              void* d_out, int out_size, void* d_ws, size_t ws_size,
                              hipStream_t stream)
{
  const float* x    = (const float*)d_in[0];
  const int*   ei   = (const int*)d_in[1];
  const float* w_in = (const float*)d_in[2];
  const float* b_in = (const float*)d_in[3];
  const float* g0w  = (const float*)d_in[4];
  const float* g0as = (const float*)d_in[5];
  const float* g0ad = (const float*)d_in[6];
  const float* g0b  = (const float*)d_in[7];
  const float* bn0g = (const float*)d_in[8];
  const float* bn0b = (const float*)d_in[9];
  const float* bn0m = (const float*)d_in[10];
  const float* bn0v = (const float*)d_in[11];
  const float* g1w  = (const float*)d_in[12];
  const float* g1as = (const float*)d_in[13];
  const float* g1ad = (const float*)d_in[14];
  const float* g1b  = (const float*)d_in[15];
  const float* bn1g = (const float*)d_in[16];
  const float* bn1b = (const float*)d_in[17];
  const float* bn1m = (const float*)d_in[18];
  const float* bn1v = (const float*)d_in[19];
  const float* w1   = (const float*)d_in[20];
  const float* b1   = (const float*)d_in[21];
  const float* w2   = (const float*)d_in[22];
  const float* b2   = (const float*)d_in[23];

  u16* wf = (u16*)d_ws;   // 2 layers x 2 hilo x 16384 bf16 = 128 KB

  prep_w_kernel<<<128, 256, 0, stream>>>(g0w, g1w, wf);
  gnn_fused_kernel<<<512, 1024, 0, stream>>>(x, ei, w_in, b_in,
      g0as, g0ad, g0b, bn0g, bn0b, bn0m, bn0v,
      g1as, g1ad, g1b, bn1g, bn1b, bn1m, bn1v,
      w1, b1, w2, b2, wf, (float*)d_out);
}